// Round 7
// baseline (184.831 us; speedup 1.0000x reference)
//
#include <hip/hip_runtime.h>
#include <math.h>

#define BB   4096
#define SS   5
#define DD   64
#define HSZ  961
#define VSA  1024
#define NT   256
#define NB   2      // batches per block
#define LNE  1e-3f

// padded h layout: P[r] = h[r-POFF] for r in [POFF, POFF+960], else 0
#define POFF 64
#define PW   1092   // max index accessed = 1091 (incl. +1-iter prefetch); 16B rows

typedef float v4f __attribute__((ext_vector_type(4)));   // native vec for nontemporal

__device__ __forceinline__ float silu_f(float x) { return x / (1.f + __expf(-x)); }

// ---- DPP wave64 sum: pure-VALU reduction, no lgkmcnt traffic ----
template <int CTRL>
__device__ __forceinline__ float dpp_add(float x) {
    int t = __builtin_amdgcn_update_dpp(0, __builtin_bit_cast(int, x),
                                        CTRL, 0xf, 0xf, false);
    return x + __builtin_bit_cast(float, t);
}
// full 64-lane sum; valid in lane 63
__device__ __forceinline__ float wave64_sum_l63(float x) {
    x = dpp_add<0x111>(x);  // row_shr:1
    x = dpp_add<0x112>(x);  // row_shr:2
    x = dpp_add<0x114>(x);  // row_shr:4
    x = dpp_add<0x118>(x);  // row_shr:8
    x = dpp_add<0x142>(x);  // row_bcast:15
    x = dpp_add<0x143>(x);  // row_bcast:31
    return x;
}

// ---- Kernel 1: sp = LN(silu(conv(symbols,h))); also emit zero-padded h ----
__global__ __launch_bounds__(NT)
void sp_kernel(const float* __restrict__ symbols, const float* __restrict__ h,
               const float* __restrict__ gamma, const float* __restrict__ beta,
               float* __restrict__ sp, float* __restrict__ hpadG)
{
    __shared__ float hpad[PW];
    __shared__ float red[4][2];
    const int s = blockIdx.x;
    const int tid = threadIdx.x;
    const int lane = tid & 63, wave = tid >> 6;

    for (int r = tid; r < PW; r += NT) {
        const float v = (r >= POFF && r <= POFF + 960) ? h[s * HSZ + (r - POFF)] : 0.f;
        hpad[r] = v;
        hpadG[s * PW + r] = v;        // padded copy for main_kernel
    }
    __syncthreads();

    const int base = 1020 - 4 * tid;
    float hw[8];
    *(float4*)&hw[0] = *(const float4*)&hpad[base];
    float acc[4] = {0.f, 0.f, 0.f, 0.f};
    const float* xp = symbols + s * DD;
#pragma unroll
    for (int c = 0; c < 16; c++) {
        *(float4*)&hw[4] = *(const float4*)&hpad[base + 4 * (c + 1)];
        const float x0 = xp[4 * c + 0];
        const float x1 = xp[4 * c + 1];
        const float x2 = xp[4 * c + 2];
        const float x3 = xp[4 * c + 3];
        acc[0] += x0 * hw[4]; acc[0] += x1 * hw[5]; acc[0] += x2 * hw[6]; acc[0] += x3 * hw[7];
        acc[1] += x0 * hw[3]; acc[1] += x1 * hw[4]; acc[1] += x2 * hw[5]; acc[1] += x3 * hw[6];
        acc[2] += x0 * hw[2]; acc[2] += x1 * hw[3]; acc[2] += x2 * hw[4]; acc[2] += x3 * hw[5];
        acc[3] += x0 * hw[1]; acc[3] += x1 * hw[2]; acc[3] += x2 * hw[3]; acc[3] += x3 * hw[4];
        hw[0] = hw[4]; hw[1] = hw[5]; hw[2] = hw[6]; hw[3] = hw[7];
    }

    float ys[4];
    float lsum = 0.f, lsq = 0.f;
#pragma unroll
    for (int j = 0; j < 4; j++) {
        ys[j] = silu_f(acc[j]);
        lsum += ys[j]; lsq += ys[j] * ys[j];
    }
    lsum = wave64_sum_l63(lsum);
    lsq  = wave64_sum_l63(lsq);
    if (lane == 63) { red[wave][0] = lsum; red[wave][1] = lsq; }
    __syncthreads();
    float s0 = 0.f, s1 = 0.f;
#pragma unroll
    for (int w = 0; w < 4; w++) { s0 += red[w][0]; s1 += red[w][1]; }
    const float mean = s0 * (1.f / VSA);
    const float rstd = rsqrtf(s1 * (1.f / VSA) - mean * mean + LNE);

    const float4 g4 = *(const float4*)&gamma[4 * tid];
    const float4 b4 = *(const float4*)&beta[4 * tid];
    float4 o;
    o.x = (ys[0] - mean) * rstd * g4.x + b4.x;
    o.y = (ys[1] - mean) * rstd * g4.y + b4.y;
    o.z = (ys[2] - mean) * rstd * g4.z + b4.z;
    o.w = (ys[3] - mean) * rstd * g4.w + b4.w;
    *(float4*)&sp[s * VSA + 4 * tid] = o;
}

// ------- Kernel 2: NB=2 batches per block --------------------------------
// R6 post-mortem: per-step sched_barrier(0) is a HARD region wall -> the
// scheduler parked the c+1 loads right before the wall, so every step ate a
// full LDS-latency stall (VALUBusy 76->41, dur 109->164 despite 0 conflicts).
// R7: replace walls with sched_group_barrier quotas per step:
// [DS_READ x3][VALU x32]. Loads for c+1 are forced to issue BEFORE the 32
// FMAs of step c (~64 cy of cover), and the quota still bounds load-hoisting
// so the R4 register explosion cannot recur (pressure bounded by order).
__global__ __launch_bounds__(NT, 2)
void main_kernel(const float* __restrict__ values, const float* __restrict__ hpadG,
                 const float* __restrict__ sp, const float* __restrict__ gamma,
                 const float* __restrict__ beta, float* __restrict__ out)
{
    __shared__ __align__(16) float hs[SS * PW];      // 21.8 KB padded h
    __shared__ __align__(16) float xs[NB][SS][DD];   // 2.5 KB block's values
    __shared__ float red[SS][NB][4][2];
    __shared__ int   scorered[NB][4][SS * SS];
    __shared__ float wbuf[NB][SS * SS];

    const int tid = threadIdx.x;
    const int lane = tid & 63, wave = tid >> 6;
    const int b0 = blockIdx.x * NB;
    const int base = 1020 - 4 * tid;

    // stage padded h: 5460 floats = 1365 float4, coalesced
    for (int i = tid; i < (SS * PW) / 4; i += NT)
        ((float4*)hs)[i] = ((const float4*)hpadG)[i];

    // stage NB*5*64 = 640 contiguous floats, coalesced float4
    if (tid < (NB * SS * DD) / 4) {
        ((float4*)xs)[tid] =
            ((const float4*)(values + (size_t)b0 * (SS * DD)))[tid];
    }
    __syncthreads();

    float vp[NB][SS][4];   // conv->silu->LN results, t = 4*tid+j

    // conv + silu for all 5 s x NB batches; everything from LDS
#pragma unroll
    for (int s = 0; s < SS; s++) {
        const float* hp  = hs + s * PW + base;
        const float* x0p = &xs[0][s][0];
        const float* x1p = &xs[1][s][0];
        // preload c=0 operands (4 ds_read_b128)
        float4 hLo = *(const float4*)hp;         // taps 4c+0..3
        float4 hHi = *(const float4*)(hp + 4);   // taps 4c+4..7
        float4 xv0 = *(const float4*)x0p;        // uniform broadcast
        float4 xv1 = *(const float4*)x1p;
        float a00 = 0.f, a01 = 0.f, a02 = 0.f, a03 = 0.f;
        float a10 = 0.f, a11 = 0.f, a12 = 0.f, a13 = 0.f;
        __builtin_amdgcn_sched_barrier(0);   // preload region boundary
#pragma unroll
        for (int c = 0; c < 16; c++) {
            // prefetch c+1 operands (3 ds_reads: 1 per-lane h, 2 uniform x)
            float4 hNx = {}, xn0 = {}, xn1 = {};
            if (c < 15) {
                hNx = *(const float4*)(hp + 4 * c + 8);   // max idx 1091 < PW
                xn0 = *(const float4*)(x0p + 4 * c + 4);
                xn1 = *(const float4*)(x1p + 4 * c + 4);
            }
            // FMAs for step c: hw[0..3]=hLo, hw[4..7]=hHi (same order as R5/R6)
            a00 += xv0.x * hHi.x; a00 += xv0.y * hHi.y; a00 += xv0.z * hHi.z; a00 += xv0.w * hHi.w;
            a01 += xv0.x * hLo.w; a01 += xv0.y * hHi.x; a01 += xv0.z * hHi.y; a01 += xv0.w * hHi.z;
            a02 += xv0.x * hLo.z; a02 += xv0.y * hLo.w; a02 += xv0.z * hHi.x; a02 += xv0.w * hHi.y;
            a03 += xv0.x * hLo.y; a03 += xv0.y * hLo.z; a03 += xv0.z * hLo.w; a03 += xv0.w * hHi.x;
            a10 += xv1.x * hHi.x; a10 += xv1.y * hHi.y; a10 += xv1.z * hHi.z; a10 += xv1.w * hHi.w;
            a11 += xv1.x * hLo.w; a11 += xv1.y * hHi.x; a11 += xv1.z * hHi.y; a11 += xv1.w * hHi.z;
            a12 += xv1.x * hLo.z; a12 += xv1.y * hLo.w; a12 += xv1.z * hHi.x; a12 += xv1.w * hHi.y;
            a13 += xv1.x * hLo.y; a13 += xv1.y * hLo.z; a13 += xv1.z * hLo.w; a13 += xv1.w * hHi.x;
            // quota groups: 3 DS_READ (the c+1 loads) BEFORE 32 VALU (step c)
            if (c < 15)
                __builtin_amdgcn_sched_group_barrier(0x100 /*DS_READ*/, 3, 0);
            __builtin_amdgcn_sched_group_barrier(0x2 /*VALU*/, 32, 0);
            // window rotate: renamed away under full unroll
            hLo = hHi; hHi = hNx;
            xv0 = xn0; xv1 = xn1;
        }
        __builtin_amdgcn_sched_barrier(0);
        // silu + LN partials per batch (pure-VALU DPP reduce)
        {
            float acc2[NB][4] = {{a00, a01, a02, a03}, {a10, a11, a12, a13}};
#pragma unroll
            for (int nb = 0; nb < NB; nb++) {
                float lsum = 0.f, lsq = 0.f;
#pragma unroll
                for (int j = 0; j < 4; j++) {
                    const float y = silu_f(acc2[nb][j]);
                    vp[nb][s][j] = y; lsum += y; lsq += y * y;
                }
                lsum = wave64_sum_l63(lsum);
                lsq  = wave64_sum_l63(lsq);
                if (lane == 63) { red[s][nb][wave][0] = lsum; red[s][nb][wave][1] = lsq; }
            }
        }
        __builtin_amdgcn_sched_barrier(0);
    }
    __syncthreads();

    // LayerNorm epilogue in registers
    const float4 g4 = *(const float4*)&gamma[4 * tid];
    const float4 b4 = *(const float4*)&beta[4 * tid];
#pragma unroll
    for (int s = 0; s < SS; s++) {
#pragma unroll
        for (int nb = 0; nb < NB; nb++) {
            float s0 = 0.f, s1 = 0.f;
#pragma unroll
            for (int w = 0; w < 4; w++) { s0 += red[s][nb][w][0]; s1 += red[s][nb][w][1]; }
            const float mean = s0 * (1.f / VSA);
            const float rstd = rsqrtf(s1 * (1.f / VSA) - mean * mean + LNE);
            vp[nb][s][0] = (vp[nb][s][0] - mean) * rstd * g4.x + b4.x;
            vp[nb][s][1] = (vp[nb][s][1] - mean) * rstd * g4.y + b4.y;
            vp[nb][s][2] = (vp[nb][s][2] - mean) * rstd * g4.z + b4.z;
            vp[nb][s][3] = (vp[nb][s][3] - mean) * rstd * g4.w + b4.w;
        }
    }

    // sp fragments (batch-independent, L1/L2-hot)
    float sp4[SS][4];
#pragma unroll
    for (int i = 0; i < SS; i++)
        *(float4*)&sp4[i][0] = *(const float4*)&sp[i * VSA + 4 * tid];

    // scores via ballot: sign(a)*sign(b) = 1 - 2*[signbits differ]
#pragma unroll
    for (int nb = 0; nb < NB; nb++) {
        int neq[SS * SS];
#pragma unroll
        for (int p = 0; p < SS * SS; p++) neq[p] = 0;
#pragma unroll
        for (int jj = 0; jj < 4; jj++) {
            unsigned long long bvi[SS];
#pragma unroll
            for (int i = 0; i < SS; i++) bvi[i] = __ballot(vp[nb][i][jj] > 0.f);
#pragma unroll
            for (int j = 0; j < SS; j++) {
                const float sjv = sp4[j][jj];
#pragma unroll
                for (int i = 0; i < SS; i++) {
                    const unsigned long long bs = __ballot(vp[nb][i][jj] + sjv > 0.f);
                    neq[j * SS + i] += (int)__popcll(bvi[i] ^ bs);
                }
            }
        }
        if (lane == 0) {
#pragma unroll
            for (int p = 0; p < SS * SS; p++) scorered[nb][wave][p] = neq[p];
        }
    }
    __syncthreads();

    // softmax over i per (nb, j) — NB*SS threads
    if (tid < NB * SS) {
        const int nb = tid / SS, j = tid - nb * SS;
        float sc[SS];
#pragma unroll
        for (int i = 0; i < SS; i++) {
            const int nq = scorered[nb][0][j * SS + i] + scorered[nb][1][j * SS + i]
                         + scorered[nb][2][j * SS + i] + scorered[nb][3][j * SS + i];
            sc[i] = 1.f - (2.f / VSA) * (float)nq;
        }
        float m = sc[0];
#pragma unroll
        for (int i = 1; i < SS; i++) m = fmaxf(m, sc[i]);
        float e[SS], ssum = 0.f;
#pragma unroll
        for (int i = 0; i < SS; i++) { e[i] = __expf(sc[i] - m); ssum += e[i]; }
        const float inv = 1.f / ssum;
#pragma unroll
        for (int i = 0; i < SS; i++) wbuf[nb][j * SS + i] = e[i] * inv;
    }
    __syncthreads();

    // out[b][j][t] = silu( (sum_i w[j][i]*vp[i][t]) * sp[j][t] )
#pragma unroll
    for (int nb = 0; nb < NB; nb++) {
        const size_t obase = (size_t)(b0 + nb) * SS * VSA + 4 * tid;
#pragma unroll
        for (int j = 0; j < SS; j++) {
            float wj[SS];
#pragma unroll
            for (int i = 0; i < SS; i++) wj[i] = wbuf[nb][j * SS + i];  // LDS broadcast
            float att[4] = {0.f, 0.f, 0.f, 0.f};
#pragma unroll
            for (int i = 0; i < SS; i++) {
                const float wi = wj[i];
#pragma unroll
                for (int e = 0; e < 4; e++) att[e] += wi * vp[nb][i][e];
            }
            v4f o;
            o.x = silu_f(att[0] * sp4[j][0]);
            o.y = silu_f(att[1] * sp4[j][1]);
            o.z = silu_f(att[2] * sp4[j][2]);
            o.w = silu_f(att[3] * sp4[j][3]);
            __builtin_nontemporal_store(o, (v4f*)&out[obase + (size_t)j * VSA]);
        }
    }
}

extern "C" void kernel_launch(void* const* d_in, const int* in_sizes, int n_in,
                              void* d_out, int out_size, void* d_ws, size_t ws_size,
                              hipStream_t stream) {
    const float* values  = (const float*)d_in[0];
    const float* h       = (const float*)d_in[1];
    const float* symbols = (const float*)d_in[2];
    const float* gamma   = (const float*)d_in[3];
    const float* beta    = (const float*)d_in[4];
    float* out   = (float*)d_out;
    float* sp    = (float*)d_ws;                 // 5*1024 floats
    float* hpadG = (float*)d_ws + SS * VSA;      // 5*1092 floats (padded h)

    sp_kernel<<<SS, NT, 0, stream>>>(symbols, h, gamma, beta, sp, hpadG);
    main_kernel<<<BB / NB, NT, 0, stream>>>(values, hpadG, sp, gamma, beta, out);
}

// Round 8
// 171.342 us; speedup vs baseline: 1.0787x; 1.0787x over previous
//
#include <hip/hip_runtime.h>
#include <math.h>

#define BB   4096
#define SS   5
#define DD   64
#define HSZ  961
#define VSA  1024
#define NT   256
#define NB   2      // batches per block, packed pairwise into v_pk_fma_f32
#define LNE  1e-3f

// padded h layout: P[r] = h[r-POFF] for r in [POFF, POFF+960], else 0
#define POFF 64
#define PW   1092   // max index accessed = 1091 (incl. +1-iter prefetch); 16B rows

typedef float v4f __attribute__((ext_vector_type(4)));   // native vec for nontemporal
typedef float v2f __attribute__((ext_vector_type(2)));   // packed pair (nb0,nb1)

__device__ __forceinline__ float silu_f(float x) { return x / (1.f + __expf(-x)); }
__device__ __forceinline__ v2f splat2(float x) { v2f r; r.x = x; r.y = x; return r; }
__device__ __forceinline__ v2f fma2(v2f a, float b, v2f c) {
    return __builtin_elementwise_fma(a, splat2(b), c);   // v_pk_fma_f32
}

// ---- DPP wave64 sum: pure-VALU reduction, no lgkmcnt traffic ----
template <int CTRL>
__device__ __forceinline__ float dpp_add(float x) {
    int t = __builtin_amdgcn_update_dpp(0, __builtin_bit_cast(int, x),
                                        CTRL, 0xf, 0xf, false);
    return x + __builtin_bit_cast(float, t);
}
// full 64-lane sum; valid in lane 63
__device__ __forceinline__ float wave64_sum_l63(float x) {
    x = dpp_add<0x111>(x);  // row_shr:1
    x = dpp_add<0x112>(x);  // row_shr:2
    x = dpp_add<0x114>(x);  // row_shr:4
    x = dpp_add<0x118>(x);  // row_shr:8
    x = dpp_add<0x142>(x);  // row_bcast:15
    x = dpp_add<0x143>(x);  // row_bcast:31
    return x;
}

// ---- Kernel 1: sp = LN(silu(conv(symbols,h))); also emit zero-padded h ----
__global__ __launch_bounds__(NT)
void sp_kernel(const float* __restrict__ symbols, const float* __restrict__ h,
               const float* __restrict__ gamma, const float* __restrict__ beta,
               float* __restrict__ sp, float* __restrict__ hpadG)
{
    __shared__ float hpad[PW];
    __shared__ float red[4][2];
    const int s = blockIdx.x;
    const int tid = threadIdx.x;
    const int lane = tid & 63, wave = tid >> 6;

    for (int r = tid; r < PW; r += NT) {
        const float v = (r >= POFF && r <= POFF + 960) ? h[s * HSZ + (r - POFF)] : 0.f;
        hpad[r] = v;
        hpadG[s * PW + r] = v;        // padded copy for main_kernel
    }
    __syncthreads();

    const int base = 1020 - 4 * tid;
    float hw[8];
    *(float4*)&hw[0] = *(const float4*)&hpad[base];
    float acc[4] = {0.f, 0.f, 0.f, 0.f};
    const float* xp = symbols + s * DD;
#pragma unroll
    for (int c = 0; c < 16; c++) {
        *(float4*)&hw[4] = *(const float4*)&hpad[base + 4 * (c + 1)];
        const float x0 = xp[4 * c + 0];
        const float x1 = xp[4 * c + 1];
        const float x2 = xp[4 * c + 2];
        const float x3 = xp[4 * c + 3];
        acc[0] += x0 * hw[4]; acc[0] += x1 * hw[5]; acc[0] += x2 * hw[6]; acc[0] += x3 * hw[7];
        acc[1] += x0 * hw[3]; acc[1] += x1 * hw[4]; acc[1] += x2 * hw[5]; acc[1] += x3 * hw[6];
        acc[2] += x0 * hw[2]; acc[2] += x1 * hw[3]; acc[2] += x2 * hw[4]; acc[2] += x3 * hw[5];
        acc[3] += x0 * hw[1]; acc[3] += x1 * hw[2]; acc[3] += x2 * hw[3]; acc[3] += x3 * hw[4];
        hw[0] = hw[4]; hw[1] = hw[5]; hw[2] = hw[6]; hw[3] = hw[7];
    }

    float ys[4];
    float lsum = 0.f, lsq = 0.f;
#pragma unroll
    for (int j = 0; j < 4; j++) {
        ys[j] = silu_f(acc[j]);
        lsum += ys[j]; lsq += ys[j] * ys[j];
    }
    lsum = wave64_sum_l63(lsum);
    lsq  = wave64_sum_l63(lsq);
    if (lane == 63) { red[wave][0] = lsum; red[wave][1] = lsq; }
    __syncthreads();
    float s0 = 0.f, s1 = 0.f;
#pragma unroll
    for (int w = 0; w < 4; w++) { s0 += red[w][0]; s1 += red[w][1]; }
    const float mean = s0 * (1.f / VSA);
    const float rstd = rsqrtf(s1 * (1.f / VSA) - mean * mean + LNE);

    const float4 g4 = *(const float4*)&gamma[4 * tid];
    const float4 b4 = *(const float4*)&beta[4 * tid];
    float4 o;
    o.x = (ys[0] - mean) * rstd * g4.x + b4.x;
    o.y = (ys[1] - mean) * rstd * g4.y + b4.y;
    o.z = (ys[2] - mean) * rstd * g4.z + b4.z;
    o.w = (ys[3] - mean) * rstd * g4.w + b4.w;
    *(float4*)&sp[s * VSA + 4 * tid] = o;
}

// ------- Kernel 2: NB=2 batches per block --------------------------------
// R7 post-mortem: wall-vs-kernel gap across rounds is monotone in power
// (VALUBusy + HBM traffic) -> DVFS throttling in the back-to-back bench
// loop; rocprof's replay gaps let clocks recover.  The wall metric is
// ENERGY-bound: minimize issued instructions.
// R8 = R6's v_pk_fma_f32 conv (halves conv FMA issue, verified bit-correct)
//    + R7's sched_group_barrier quota pipeline (verified no-stall/no-spill):
// per step  [DS_READ x3][VALU x16].
__global__ __launch_bounds__(NT, 2)
void main_kernel(const float* __restrict__ values, const float* __restrict__ hpadG,
                 const float* __restrict__ sp, const float* __restrict__ gamma,
                 const float* __restrict__ beta, float* __restrict__ out)
{
    __shared__ __align__(16) float hs[SS * PW];       // 21.8 KB padded h
    __shared__ __align__(16) float xsI[SS][DD][NB];   // 2.5 KB values, nb-interleaved
    __shared__ float red[SS][NB][4][2];
    __shared__ int   scorered[NB][4][SS * SS];
    __shared__ float wbuf[NB][SS * SS];

    const int tid = threadIdx.x;
    const int lane = tid & 63, wave = tid >> 6;
    const int b0 = blockIdx.x * NB;
    const int base = 1020 - 4 * tid;

    // stage padded h: 5460 floats = 1365 float4, coalesced
    for (int i = tid; i < (SS * PW) / 4; i += NT)
        ((float4*)hs)[i] = ((const float4*)hpadG)[i];

    // stage values nb-interleaved: xsI[s][d] = {v[b0][s][d], v[b0+1][s][d]}
    for (int i = tid; i < SS * DD; i += NT) {
        v2f v;
        v.x = values[(size_t)(b0 + 0) * (SS * DD) + i];
        v.y = values[(size_t)(b0 + 1) * (SS * DD) + i];
        ((v2f*)xsI)[i] = v;
    }
    __syncthreads();

    float vp[NB][SS][4];   // conv->silu->LN results, t = 4*tid+j

    // conv + silu for all 5 s; both batches packed per v_pk_fma_f32
#pragma unroll
    for (int s = 0; s < SS; s++) {
        const float* hp = hs + s * PW + base;
        const v2f*   xp = (const v2f*)&xsI[s][0][0];
        // preload c=0 operands (4 ds_read_b128)
        float4 hLo = *(const float4*)hp;          // taps 4c+0..3
        float4 hHi = *(const float4*)(hp + 4);    // taps 4c+4..7
        float4 xq0 = *(const float4*)(xp + 0);    // pairs d=0,1
        float4 xq1 = *(const float4*)(xp + 2);    // pairs d=2,3
        v2f x0 = {xq0.x, xq0.y}, x1 = {xq0.z, xq0.w};
        v2f x2 = {xq1.x, xq1.y}, x3 = {xq1.z, xq1.w};
        v2f a0 = {}, a1 = {}, a2 = {}, a3 = {};
        __builtin_amdgcn_sched_barrier(0);   // preload region boundary
#pragma unroll
        for (int c = 0; c < 16; c++) {
            // prefetch c+1 operands (3 ds_read_b128: 1 per-lane h, 2 uniform x)
            float4 hNx = {}, xq0n = {}, xq1n = {};
            if (c < 15) {
                hNx  = *(const float4*)(hp + 4 * c + 8);     // max idx 1091 < PW
                xq0n = *(const float4*)(xp + 4 * c + 4);     // pairs d=4c+4,4c+5
                xq1n = *(const float4*)(xp + 4 * c + 6);     // pairs d=4c+6,4c+7
            }
            // 16 pk FMAs for step c; per-lane chain order == scalar version
            a0 = fma2(x0, hHi.x, a0); a0 = fma2(x1, hHi.y, a0);
            a0 = fma2(x2, hHi.z, a0); a0 = fma2(x3, hHi.w, a0);
            a1 = fma2(x0, hLo.w, a1); a1 = fma2(x1, hHi.x, a1);
            a1 = fma2(x2, hHi.y, a1); a1 = fma2(x3, hHi.z, a1);
            a2 = fma2(x0, hLo.z, a2); a2 = fma2(x1, hLo.w, a2);
            a2 = fma2(x2, hHi.x, a2); a2 = fma2(x3, hHi.y, a2);
            a3 = fma2(x0, hLo.y, a3); a3 = fma2(x1, hLo.z, a3);
            a3 = fma2(x2, hLo.w, a3); a3 = fma2(x3, hHi.x, a3);
            // quota groups: 3 DS_READ (c+1 loads) BEFORE the 16 pk FMAs
            if (c < 15)
                __builtin_amdgcn_sched_group_barrier(0x100 /*DS_READ*/, 3, 0);
            __builtin_amdgcn_sched_group_barrier(0x2 /*VALU*/, 16, 0);
            // window rotate: renamed away under full unroll
            hLo = hHi; hHi = hNx;
            x0 = (v2f){xq0n.x, xq0n.y}; x1 = (v2f){xq0n.z, xq0n.w};
            x2 = (v2f){xq1n.x, xq1n.y}; x3 = (v2f){xq1n.z, xq1n.w};
        }
        __builtin_amdgcn_sched_barrier(0);
        // silu + LN partials per batch (pure-VALU DPP reduce)
        {
            const v2f accv[4] = {a0, a1, a2, a3};
#pragma unroll
            for (int nb = 0; nb < NB; nb++) {
                float lsum = 0.f, lsq = 0.f;
#pragma unroll
                for (int j = 0; j < 4; j++) {
                    const float y = silu_f(accv[j][nb]);
                    vp[nb][s][j] = y; lsum += y; lsq += y * y;
                }
                lsum = wave64_sum_l63(lsum);
                lsq  = wave64_sum_l63(lsq);
                if (lane == 63) { red[s][nb][wave][0] = lsum; red[s][nb][wave][1] = lsq; }
            }
        }
        __builtin_amdgcn_sched_barrier(0);
    }
    __syncthreads();

    // LayerNorm epilogue in registers
    const float4 g4 = *(const float4*)&gamma[4 * tid];
    const float4 b4 = *(const float4*)&beta[4 * tid];
#pragma unroll
    for (int s = 0; s < SS; s++) {
#pragma unroll
        for (int nb = 0; nb < NB; nb++) {
            float s0 = 0.f, s1 = 0.f;
#pragma unroll
            for (int w = 0; w < 4; w++) { s0 += red[s][nb][w][0]; s1 += red[s][nb][w][1]; }
            const float mean = s0 * (1.f / VSA);
            const float rstd = rsqrtf(s1 * (1.f / VSA) - mean * mean + LNE);
            vp[nb][s][0] = (vp[nb][s][0] - mean) * rstd * g4.x + b4.x;
            vp[nb][s][1] = (vp[nb][s][1] - mean) * rstd * g4.y + b4.y;
            vp[nb][s][2] = (vp[nb][s][2] - mean) * rstd * g4.z + b4.z;
            vp[nb][s][3] = (vp[nb][s][3] - mean) * rstd * g4.w + b4.w;
        }
    }

    // sp fragments (batch-independent, L1/L2-hot)
    float sp4[SS][4];
#pragma unroll
    for (int i = 0; i < SS; i++)
        *(float4*)&sp4[i][0] = *(const float4*)&sp[i * VSA + 4 * tid];

    // scores via ballot: sign(a)*sign(b) = 1 - 2*[signbits differ]
#pragma unroll
    for (int nb = 0; nb < NB; nb++) {
        int neq[SS * SS];
#pragma unroll
        for (int p = 0; p < SS * SS; p++) neq[p] = 0;
#pragma unroll
        for (int jj = 0; jj < 4; jj++) {
            unsigned long long bvi[SS];
#pragma unroll
            for (int i = 0; i < SS; i++) bvi[i] = __ballot(vp[nb][i][jj] > 0.f);
#pragma unroll
            for (int j = 0; j < SS; j++) {
                const float sjv = sp4[j][jj];
#pragma unroll
                for (int i = 0; i < SS; i++) {
                    const unsigned long long bs = __ballot(vp[nb][i][jj] + sjv > 0.f);
                    neq[j * SS + i] += (int)__popcll(bvi[i] ^ bs);
                }
            }
        }
        if (lane == 0) {
#pragma unroll
            for (int p = 0; p < SS * SS; p++) scorered[nb][wave][p] = neq[p];
        }
    }
    __syncthreads();

    // softmax over i per (nb, j) — NB*SS threads
    if (tid < NB * SS) {
        const int nb = tid / SS, j = tid - nb * SS;
        float sc[SS];
#pragma unroll
        for (int i = 0; i < SS; i++) {
            const int nq = scorered[nb][0][j * SS + i] + scorered[nb][1][j * SS + i]
                         + scorered[nb][2][j * SS + i] + scorered[nb][3][j * SS + i];
            sc[i] = 1.f - (2.f / VSA) * (float)nq;
        }
        float m = sc[0];
#pragma unroll
        for (int i = 1; i < SS; i++) m = fmaxf(m, sc[i]);
        float e[SS], ssum = 0.f;
#pragma unroll
        for (int i = 0; i < SS; i++) { e[i] = __expf(sc[i] - m); ssum += e[i]; }
        const float inv = 1.f / ssum;
#pragma unroll
        for (int i = 0; i < SS; i++) wbuf[nb][j * SS + i] = e[i] * inv;
    }
    __syncthreads();

    // out[b][j][t] = silu( (sum_i w[j][i]*vp[i][t]) * sp[j][t] )
#pragma unroll
    for (int nb = 0; nb < NB; nb++) {
        const size_t obase = (size_t)(b0 + nb) * SS * VSA + 4 * tid;
#pragma unroll
        for (int j = 0; j < SS; j++) {
            float wj[SS];
#pragma unroll
            for (int i = 0; i < SS; i++) wj[i] = wbuf[nb][j * SS + i];  // LDS broadcast
            float att[4] = {0.f, 0.f, 0.f, 0.f};
#pragma unroll
            for (int i = 0; i < SS; i++) {
                const float wi = wj[i];
#pragma unroll
                for (int e = 0; e < 4; e++) att[e] += wi * vp[nb][i][e];
            }
            v4f o;
            o.x = silu_f(att[0] * sp4[j][0]);
            o.y = silu_f(att[1] * sp4[j][1]);
            o.z = silu_f(att[2] * sp4[j][2]);
            o.w = silu_f(att[3] * sp4[j][3]);
            __builtin_nontemporal_store(o, (v4f*)&out[obase + (size_t)j * VSA]);
        }
    }
}

extern "C" void kernel_launch(void* const* d_in, const int* in_sizes, int n_in,
                              void* d_out, int out_size, void* d_ws, size_t ws_size,
                              hipStream_t stream) {
    const float* values  = (const float*)d_in[0];
    const float* h       = (const float*)d_in[1];
    const float* symbols = (const float*)d_in[2];
    const float* gamma   = (const float*)d_in[3];
    const float* beta    = (const float*)d_in[4];
    float* out   = (float*)d_out;
    float* sp    = (float*)d_ws;                 // 5*1024 floats
    float* hpadG = (float*)d_ws + SS * VSA;      // 5*1092 floats (padded h)

    sp_kernel<<<SS, NT, 0, stream>>>(symbols, h, gamma, beta, sp, hpadG);
    main_kernel<<<BB / NB, NT, 0, stream>>>(values, hpadG, sp, gamma, beta, out);
}

// Round 9
// 155.472 us; speedup vs baseline: 1.1888x; 1.1021x over previous
//
#include <hip/hip_runtime.h>
#include <math.h>

#define BB   4096
#define SS   5
#define DD   64
#define HSZ  961
#define VSA  1024
#define NT   256
#define NB   2      // batches per block, packed pairwise (v2f = (nb0,nb1))
#define LNE  1e-3f

// padded h layout: P[r] = h[r-POFF] for r in [POFF, POFF+960], else 0
#define POFF 64
#define PW   1092   // max index accessed = 1091 (incl. +1-iter prefetch); 16B rows

typedef float v4f __attribute__((ext_vector_type(4)));   // native vec for nontemporal
typedef float v2f __attribute__((ext_vector_type(2)));   // packed pair (nb0,nb1)

// v_rcp_f32 (~1 ulp) instead of IEEE '/': default HIP divide expands to
// div_scale/div_fmas/div_fixup (~10 insts).  80 silus/thread made that ~800
// insts -- the single biggest energy block after the conv.
__device__ __forceinline__ float rcp_f(float x) { return __builtin_amdgcn_rcpf(x); }
__device__ __forceinline__ float silu_f(float x) { return x * rcp_f(1.f + __expf(-x)); }
__device__ __forceinline__ v2f splat2(float x) { v2f r; r.x = x; r.y = x; return r; }
__device__ __forceinline__ v2f fma2(v2f a, float b, v2f c) {
    return __builtin_elementwise_fma(a, splat2(b), c);   // v_pk_fma_f32
}
__device__ __forceinline__ v2f fma2v(v2f a, v2f b, v2f c) {
    return __builtin_elementwise_fma(a, b, c);
}
__device__ __forceinline__ v2f silu2(v2f x) {            // both nb at once
    v2f e; e.x = __expf(-x.x); e.y = __expf(-x.y);
    v2f d = e + splat2(1.f);
    v2f rc; rc.x = rcp_f(d.x); rc.y = rcp_f(d.y);
    return x * rc;
}
// component select with compile-time nb (all uses under full unroll)
__device__ __forceinline__ float c2(v2f v, int nb) { return nb == 0 ? v.x : v.y; }

// ---- DPP wave64 sum: pure-VALU reduction, no lgkmcnt traffic ----
template <int CTRL>
__device__ __forceinline__ float dpp_add(float x) {
    int t = __builtin_amdgcn_update_dpp(0, __builtin_bit_cast(int, x),
                                        CTRL, 0xf, 0xf, false);
    return x + __builtin_bit_cast(float, t);
}
__device__ __forceinline__ float wave64_sum_l63(float x) {
    x = dpp_add<0x111>(x);  // row_shr:1
    x = dpp_add<0x112>(x);  // row_shr:2
    x = dpp_add<0x114>(x);  // row_shr:4
    x = dpp_add<0x118>(x);  // row_shr:8
    x = dpp_add<0x142>(x);  // row_bcast:15
    x = dpp_add<0x143>(x);  // row_bcast:31
    return x;
}

// ---- Kernel 1: sp = LN(silu(conv(symbols,h))); also emit zero-padded h ----
__global__ __launch_bounds__(NT)
void sp_kernel(const float* __restrict__ symbols, const float* __restrict__ h,
               const float* __restrict__ gamma, const float* __restrict__ beta,
               float* __restrict__ sp, float* __restrict__ hpadG)
{
    __shared__ float hpad[PW];
    __shared__ float red[4][2];
    const int s = blockIdx.x;
    const int tid = threadIdx.x;
    const int lane = tid & 63, wave = tid >> 6;

    for (int r = tid; r < PW; r += NT) {
        const float v = (r >= POFF && r <= POFF + 960) ? h[s * HSZ + (r - POFF)] : 0.f;
        hpad[r] = v;
        hpadG[s * PW + r] = v;        // padded copy for main_kernel
    }
    __syncthreads();

    const int base = 1020 - 4 * tid;
    float hw[8];
    *(float4*)&hw[0] = *(const float4*)&hpad[base];
    float acc[4] = {0.f, 0.f, 0.f, 0.f};
    const float* xp = symbols + s * DD;
#pragma unroll
    for (int c = 0; c < 16; c++) {
        *(float4*)&hw[4] = *(const float4*)&hpad[base + 4 * (c + 1)];
        const float x0 = xp[4 * c + 0];
        const float x1 = xp[4 * c + 1];
        const float x2 = xp[4 * c + 2];
        const float x3 = xp[4 * c + 3];
        acc[0] += x0 * hw[4]; acc[0] += x1 * hw[5]; acc[0] += x2 * hw[6]; acc[0] += x3 * hw[7];
        acc[1] += x0 * hw[3]; acc[1] += x1 * hw[4]; acc[1] += x2 * hw[5]; acc[1] += x3 * hw[6];
        acc[2] += x0 * hw[2]; acc[2] += x1 * hw[3]; acc[2] += x2 * hw[4]; acc[2] += x3 * hw[5];
        acc[3] += x0 * hw[1]; acc[3] += x1 * hw[2]; acc[3] += x2 * hw[3]; acc[3] += x3 * hw[4];
        hw[0] = hw[4]; hw[1] = hw[5]; hw[2] = hw[6]; hw[3] = hw[7];
    }

    float ys[4];
    float lsum = 0.f, lsq = 0.f;
#pragma unroll
    for (int j = 0; j < 4; j++) {
        ys[j] = silu_f(acc[j]);
        lsum += ys[j]; lsq += ys[j] * ys[j];
    }
    lsum = wave64_sum_l63(lsum);
    lsq  = wave64_sum_l63(lsq);
    if (lane == 63) { red[wave][0] = lsum; red[wave][1] = lsq; }
    __syncthreads();
    float s0 = 0.f, s1 = 0.f;
#pragma unroll
    for (int w = 0; w < 4; w++) { s0 += red[w][0]; s1 += red[w][1]; }
    const float mean = s0 * (1.f / VSA);
    const float rstd = rsqrtf(s1 * (1.f / VSA) - mean * mean + LNE);

    const float4 g4 = *(const float4*)&gamma[4 * tid];
    const float4 b4 = *(const float4*)&beta[4 * tid];
    float4 o;
    o.x = (ys[0] - mean) * rstd * g4.x + b4.x;
    o.y = (ys[1] - mean) * rstd * g4.y + b4.y;
    o.z = (ys[2] - mean) * rstd * g4.z + b4.z;
    o.w = (ys[3] - mean) * rstd * g4.w + b4.w;
    *(float4*)&sp[s * VSA + 4 * tid] = o;
}

// ------- Kernel 2: NB=2 batches per block --------------------------------
// R8 post-mortem: wall is ENERGY-bound (DVFS): R6(kernel 164us) == R8
// (kernel 93us) in wall (~170) at equal inst counts; R5/R7 (+1280 insts)
// both ~186.  => minimize issued instructions, latency secondary.
// R9 cuts ~1100 insts/thread, conv untouched (R8's proven structure):
//  - silu via v_rcp (IEEE '/' was ~10 insts x 80 silus)
//  - vp kept nb-packed (v2f) end-to-end: pk LN, pk att, paired silu
//  - ballot: sign(vp+sp) == (vp > -sp); negation folds into v_cmp src
//    modifier -> removes 200 v_add
__global__ __launch_bounds__(NT, 2)
void main_kernel(const float* __restrict__ values, const float* __restrict__ hpadG,
                 const float* __restrict__ sp, const float* __restrict__ gamma,
                 const float* __restrict__ beta, float* __restrict__ out)
{
    __shared__ __align__(16) float hs[SS * PW];       // 21.8 KB padded h
    __shared__ __align__(16) float xsI[SS][DD][NB];   // 2.5 KB values, nb-interleaved
    __shared__ float red[SS][NB][4][2];
    __shared__ int   scorered[NB][4][SS * SS];
    __shared__ __align__(8) float wbufP[SS * SS][2];  // softmax weights, nb-interleaved

    const int tid = threadIdx.x;
    const int lane = tid & 63, wave = tid >> 6;
    const int b0 = blockIdx.x * NB;
    const int base = 1020 - 4 * tid;

    // stage padded h: 5460 floats = 1365 float4, coalesced
    for (int i = tid; i < (SS * PW) / 4; i += NT)
        ((float4*)hs)[i] = ((const float4*)hpadG)[i];

    // stage values nb-interleaved: xsI[s][d] = {v[b0][s][d], v[b0+1][s][d]}
    for (int i = tid; i < SS * DD; i += NT) {
        v2f v;
        v.x = values[(size_t)(b0 + 0) * (SS * DD) + i];
        v.y = values[(size_t)(b0 + 1) * (SS * DD) + i];
        ((v2f*)xsI)[i] = v;
    }
    __syncthreads();

    v2f vpP[SS][4];   // conv->silu->LN results, nb-packed; t = 4*tid+j

    // conv + silu for all 5 s; both batches packed per v_pk_fma_f32
#pragma unroll
    for (int s = 0; s < SS; s++) {
        const float* hp = hs + s * PW + base;
        const v2f*   xp = (const v2f*)&xsI[s][0][0];
        // preload c=0 operands (4 ds_read_b128)
        float4 hLo = *(const float4*)hp;          // taps 4c+0..3
        float4 hHi = *(const float4*)(hp + 4);    // taps 4c+4..7
        float4 xq0 = *(const float4*)(xp + 0);    // pairs d=0,1
        float4 xq1 = *(const float4*)(xp + 2);    // pairs d=2,3
        v2f x0 = {xq0.x, xq0.y}, x1 = {xq0.z, xq0.w};
        v2f x2 = {xq1.x, xq1.y}, x3 = {xq1.z, xq1.w};
        v2f a0 = {}, a1 = {}, a2 = {}, a3 = {};
        __builtin_amdgcn_sched_barrier(0);   // preload region boundary
#pragma unroll
        for (int c = 0; c < 16; c++) {
            // prefetch c+1 operands (3 ds_read_b128: 1 per-lane h, 2 uniform x)
            float4 hNx = {}, xq0n = {}, xq1n = {};
            if (c < 15) {
                hNx  = *(const float4*)(hp + 4 * c + 8);     // max idx 1091 < PW
                xq0n = *(const float4*)(xp + 4 * c + 4);     // pairs d=4c+4,4c+5
                xq1n = *(const float4*)(xp + 4 * c + 6);     // pairs d=4c+6,4c+7
            }
            // 16 pk FMAs for step c; per-lane chain order == scalar version
            a0 = fma2(x0, hHi.x, a0); a0 = fma2(x1, hHi.y, a0);
            a0 = fma2(x2, hHi.z, a0); a0 = fma2(x3, hHi.w, a0);
            a1 = fma2(x0, hLo.w, a1); a1 = fma2(x1, hHi.x, a1);
            a1 = fma2(x2, hHi.y, a1); a1 = fma2(x3, hHi.z, a1);
            a2 = fma2(x0, hLo.z, a2); a2 = fma2(x1, hLo.w, a2);
            a2 = fma2(x2, hHi.x, a2); a2 = fma2(x3, hHi.y, a2);
            a3 = fma2(x0, hLo.y, a3); a3 = fma2(x1, hLo.z, a3);
            a3 = fma2(x2, hLo.w, a3); a3 = fma2(x3, hHi.x, a3);
            // quota groups: 3 DS_READ (c+1 loads) BEFORE the 16 pk FMAs
            if (c < 15)
                __builtin_amdgcn_sched_group_barrier(0x100 /*DS_READ*/, 3, 0);
            __builtin_amdgcn_sched_group_barrier(0x2 /*VALU*/, 16, 0);
            // window rotate: renamed away under full unroll
            hLo = hHi; hHi = hNx;
            x0 = (v2f){xq0n.x, xq0n.y}; x1 = (v2f){xq0n.z, xq0n.w};
            x2 = (v2f){xq1n.x, xq1n.y}; x3 = (v2f){xq1n.z, xq1n.w};
        }
        __builtin_amdgcn_sched_barrier(0);
        // silu + LN partials, both nb packed per op
        {
            v2f y0 = silu2(a0), y1 = silu2(a1), y2 = silu2(a2), y3 = silu2(a3);
            vpP[s][0] = y0; vpP[s][1] = y1; vpP[s][2] = y2; vpP[s][3] = y3;
            v2f ls = ((y0 + y1) + y2) + y3;
            v2f lq = y0 * y0;
            lq = fma2v(y1, y1, lq); lq = fma2v(y2, y2, lq); lq = fma2v(y3, y3, lq);
            const float S0 = wave64_sum_l63(ls.x), Q0 = wave64_sum_l63(lq.x);
            const float S1 = wave64_sum_l63(ls.y), Q1 = wave64_sum_l63(lq.y);
            if (lane == 63) {
                red[s][0][wave][0] = S0; red[s][0][wave][1] = Q0;
                red[s][1][wave][0] = S1; red[s][1][wave][1] = Q1;
            }
        }
        __builtin_amdgcn_sched_barrier(0);
    }
    __syncthreads();

    // LayerNorm epilogue: pk over the nb pair
    const float4 g4 = *(const float4*)&gamma[4 * tid];
    const float4 b4 = *(const float4*)&beta[4 * tid];
#pragma unroll
    for (int s = 0; s < SS; s++) {
        float s00 = 0.f, q00 = 0.f, s01 = 0.f, q01 = 0.f;
#pragma unroll
        for (int w = 0; w < 4; w++) {
            s00 += red[s][0][w][0]; q00 += red[s][0][w][1];
            s01 += red[s][1][w][0]; q01 += red[s][1][w][1];
        }
        const float m0 = s00 * (1.f / VSA), m1 = s01 * (1.f / VSA);
        const float r0 = rsqrtf(q00 * (1.f / VSA) - m0 * m0 + LNE);
        const float r1 = rsqrtf(q01 * (1.f / VSA) - m1 * m1 + LNE);
        v2f mean2; mean2.x = m0; mean2.y = m1;
        v2f rstd2; rstd2.x = r0; rstd2.y = r1;
        vpP[s][0] = fma2((vpP[s][0] - mean2) * rstd2, g4.x, splat2(b4.x));
        vpP[s][1] = fma2((vpP[s][1] - mean2) * rstd2, g4.y, splat2(b4.y));
        vpP[s][2] = fma2((vpP[s][2] - mean2) * rstd2, g4.z, splat2(b4.z));
        vpP[s][3] = fma2((vpP[s][3] - mean2) * rstd2, g4.w, splat2(b4.w));
    }

    // sp fragments (batch-independent, L1/L2-hot)
    float sp4[SS][4];
#pragma unroll
    for (int i = 0; i < SS; i++)
        *(float4*)&sp4[i][0] = *(const float4*)&sp[i * VSA + 4 * tid];

    // scores via ballot: sign(a)*sign(b) = 1 - 2*[signbits differ]
    // sign(vp+sp) == (vp > -sp); '-' folds into v_cmp input modifier
#pragma unroll
    for (int nb = 0; nb < NB; nb++) {
        int neq[SS * SS];
#pragma unroll
        for (int p = 0; p < SS * SS; p++) neq[p] = 0;
#pragma unroll
        for (int jj = 0; jj < 4; jj++) {
            unsigned long long bvi[SS];
#pragma unroll
            for (int i = 0; i < SS; i++) bvi[i] = __ballot(c2(vpP[i][jj], nb) > 0.f);
#pragma unroll
            for (int j = 0; j < SS; j++) {
                const float sjv = sp4[j][jj];
#pragma unroll
                for (int i = 0; i < SS; i++) {
                    const unsigned long long bs = __ballot(c2(vpP[i][jj], nb) > -sjv);
                    neq[j * SS + i] += (int)__popcll(bvi[i] ^ bs);
                }
            }
        }
        if (lane == 0) {
#pragma unroll
            for (int p = 0; p < SS * SS; p++) scorered[nb][wave][p] = neq[p];
        }
    }
    __syncthreads();

    // softmax over i per (nb, j) — NB*SS threads
    if (tid < NB * SS) {
        const int nb = tid / SS, j = tid - nb * SS;
        float sc[SS];
#pragma unroll
        for (int i = 0; i < SS; i++) {
            const int nq = scorered[nb][0][j * SS + i] + scorered[nb][1][j * SS + i]
                         + scorered[nb][2][j * SS + i] + scorered[nb][3][j * SS + i];
            sc[i] = 1.f - (2.f / VSA) * (float)nq;
        }
        float m = sc[0];
#pragma unroll
        for (int i = 1; i < SS; i++) m = fmaxf(m, sc[i]);
        float e[SS], ssum = 0.f;
#pragma unroll
        for (int i = 0; i < SS; i++) { e[i] = __expf(sc[i] - m); ssum += e[i]; }
        const float inv = rcp_f(ssum);
#pragma unroll
        for (int i = 0; i < SS; i++) wbufP[j * SS + i][nb] = e[i] * inv;
    }
    __syncthreads();

    // out[b][j][t] = silu( (sum_i w[j][i]*vp[i][t]) * sp[j][t] ), pk over nb
    const size_t obase0 = (size_t)(b0 + 0) * SS * VSA + 4 * tid;
    const size_t obase1 = (size_t)(b0 + 1) * SS * VSA + 4 * tid;
#pragma unroll
    for (int j = 0; j < SS; j++) {
        v2f wp[SS];
#pragma unroll
        for (int i = 0; i < SS; i++) wp[i] = *(const v2f*)&wbufP[j * SS + i][0];
        v2f att[4] = {};
#pragma unroll
        for (int i = 0; i < SS; i++) {
#pragma unroll
            for (int e = 0; e < 4; e++) att[e] = fma2v(wp[i], vpP[i][e], att[e]);
        }
        v2f r[4];
#pragma unroll
        for (int e = 0; e < 4; e++) r[e] = silu2(att[e] * splat2(sp4[j][e]));
        v4f o0; o0.x = r[0].x; o0.y = r[1].x; o0.z = r[2].x; o0.w = r[3].x;
        v4f o1; o1.x = r[0].y; o1.y = r[1].y; o1.z = r[2].y; o1.w = r[3].y;
        __builtin_nontemporal_store(o0, (v4f*)&out[obase0 + (size_t)j * VSA]);
        __builtin_nontemporal_store(o1, (v4f*)&out[obase1 + (size_t)j * VSA]);
    }
}

extern "C" void kernel_launch(void* const* d_in, const int* in_sizes, int n_in,
                              void* d_out, int out_size, void* d_ws, size_t ws_size,
                              hipStream_t stream) {
    const float* values  = (const float*)d_in[0];
    const float* h       = (const float*)d_in[1];
    const float* symbols = (const float*)d_in[2];
    const float* gamma   = (const float*)d_in[3];
    const float* beta    = (const float*)d_in[4];
    float* out   = (float*)d_out;
    float* sp    = (float*)d_ws;                 // 5*1024 floats
    float* hpadG = (float*)d_ws + SS * VSA;      // 5*1092 floats (padded h)

    sp_kernel<<<SS, NT, 0, stream>>>(symbols, h, gamma, beta, sp, hpadG);
    main_kernel<<<BB / NB, NT, 0, stream>>>(values, hpadG, sp, gamma, beta, out);
}